// Round 2
// baseline (522.743 us; speedup 1.0000x reference)
//
#include <hip/hip_runtime.h>
#include <hip/hip_bf16.h>

#define N 8192
#define D 128
#define BM 128
#define BN 128

typedef __bf16 bf16x8 __attribute__((ext_vector_type(8)));
typedef __bf16 bf16x2 __attribute__((ext_vector_type(2)));
typedef float f32x4 __attribute__((ext_vector_type(4)));

// Prep: Wb = bf16(W) ; sq[i] = sum_k W[i][k]^2 ; copy W to out+1 ; zero out[0]
// One wave per row (lane handles 2 elements of D=128).
__global__ __launch_bounds__(256) void prep_kernel(const float* __restrict__ W,
                                                   float* __restrict__ out,
                                                   float* __restrict__ sq,
                                                   __bf16* __restrict__ Wb) {
    const int wave = threadIdx.x >> 6;
    const int lane = threadIdx.x & 63;
    const int row = blockIdx.x * 4 + wave;
    const size_t base = (size_t)row * D + lane * 2;
    const float2 v = *(const float2*)(&W[base]);
    out[1 + base] = v.x;           // out+1 breaks 8B alignment; scalar stores
    out[2 + base] = v.y;
    bf16x2 b;
    b[0] = (__bf16)v.x;
    b[1] = (__bf16)v.y;
    *(bf16x2*)(&Wb[base]) = b;
    float s = v.x * v.x + v.y * v.y;
    for (int off = 32; off > 0; off >>= 1) s += __shfl_down(s, off, 64);
    if (lane == 0) sq[row] = s;
    if (row == 0 && threadIdx.x == 0) out[0] = 0.0f;
}

// No LDS, no barriers: MFMA fragments loaded directly from bf16 W (cached),
// A streamed once in the epilogue.
__global__ __launch_bounds__(256) void lap_kernel(const float* __restrict__ A,
                                                  const __bf16* __restrict__ Wb,
                                                  const float* __restrict__ sq,
                                                  float* __restrict__ out) {
    const int tid = threadIdx.x;
    const int wave = tid >> 6;
    const int lane = tid & 63;
    const int wr = (wave >> 1) * 64;   // wave row offset within 128-tile
    const int wc = (wave & 1) * 64;    // wave col offset within 128-tile
    const int l15 = lane & 15;
    const int quad = lane >> 4;
    const int i0 = blockIdx.y * BM;
    const int j0 = blockIdx.x * BN;

    // A/B fragment layout for mfma_f32_16x16x32_bf16: [m = lane&15][k = quad*8 + j]
    // -> 16 contiguous bytes per lane, straight from global bf16 W.
    const __bf16* Afrag = Wb + (size_t)(i0 + wr + l15) * D + quad * 8;
    const __bf16* Bfrag = Wb + (size_t)(j0 + wc + l15) * D + quad * 8;

    f32x4 acc[4][4] = {};
#pragma unroll
    for (int kk = 0; kk < D; kk += 32) {
        bf16x8 a[4], b[4];
#pragma unroll
        for (int ti = 0; ti < 4; ++ti)
            a[ti] = *(const bf16x8*)(Afrag + (size_t)(ti * 16) * D + kk);
#pragma unroll
        for (int tj = 0; tj < 4; ++tj)
            b[tj] = *(const bf16x8*)(Bfrag + (size_t)(tj * 16) * D + kk);
#pragma unroll
        for (int ti = 0; ti < 4; ++ti)
#pragma unroll
            for (int tj = 0; tj < 4; ++tj)
                acc[ti][tj] = __builtin_amdgcn_mfma_f32_16x16x32_bf16(a[ti], b[tj], acc[ti][tj], 0, 0, 0);
    }

    // Epilogue: dist = sqrt(max(sq_i + sq_j - 2g, 0)); local += A * dist
    // C/D mapping (m89-verified): col = lane&15, row = quad*4 + reg
    float sqi[4][4];
#pragma unroll
    for (int ti = 0; ti < 4; ++ti)
#pragma unroll
        for (int r = 0; r < 4; ++r)
            sqi[ti][r] = sq[i0 + wr + ti * 16 + quad * 4 + r];

    float local = 0.0f;
#pragma unroll
    for (int ti = 0; ti < 4; ++ti) {
#pragma unroll
        for (int tj = 0; tj < 4; ++tj) {
            const int colg = j0 + wc + tj * 16 + l15;
            const float sqj = sq[colg];
            const float* Arow = A + (size_t)(i0 + wr + ti * 16 + quad * 4) * N + colg;
#pragma unroll
            for (int r = 0; r < 4; ++r) {
                const float g = acc[ti][tj][r];
                const float d2 = sqi[ti][r] + sqj - 2.0f * g;
                const float dist = sqrtf(fmaxf(d2, 0.0f));
                local += Arow[(size_t)r * N] * dist;
            }
        }
    }

    // Block reduce + one atomic per block
    for (int off = 32; off > 0; off >>= 1) local += __shfl_down(local, off, 64);
    __shared__ float red[4];
    if (lane == 0) red[wave] = local;
    __syncthreads();
    if (tid == 0) atomicAdd(out, red[0] + red[1] + red[2] + red[3]);
}

extern "C" void kernel_launch(void* const* d_in, const int* in_sizes, int n_in,
                              void* d_out, int out_size, void* d_ws, size_t ws_size,
                              hipStream_t stream) {
    const float* A = (const float*)d_in[0];
    const float* W = (const float*)d_in[1];
    float* out = (float*)d_out;
    float* sq = (float*)d_ws;                         // 8192 floats = 32 KB
    __bf16* Wb = (__bf16*)((char*)d_ws + 32 * 1024);  // 8192*128 bf16 = 2 MB

    prep_kernel<<<N / 4, 256, 0, stream>>>(W, out, sq, Wb);
    dim3 grid(N / BN, N / BM);
    lap_kernel<<<grid, 256, 0, stream>>>(A, Wb, sq, out);
}

// Round 3
// 401.640 us; speedup vs baseline: 1.3015x; 1.3015x over previous
//
#include <hip/hip_runtime.h>
#include <hip/hip_bf16.h>

#define N 8192
#define D 128
#define BM 128
#define BN 128
#define DSTRIDE 132   // bf16 dist tile stride: 132*2=264 B/row -> conflict-free patterns

typedef __bf16 bf16x8 __attribute__((ext_vector_type(8)));
typedef __bf16 bf16x4 __attribute__((ext_vector_type(4)));
typedef __bf16 bf16x2 __attribute__((ext_vector_type(2)));
typedef float f32x4 __attribute__((ext_vector_type(4)));

// Prep: Wb = bf16(W) ; sq[i] = sum_k W[i][k]^2 ; copy W to out+1 ; zero out[0]
__global__ __launch_bounds__(256) void prep_kernel(const float* __restrict__ W,
                                                   float* __restrict__ out,
                                                   float* __restrict__ sq,
                                                   __bf16* __restrict__ Wb) {
    const int wave = threadIdx.x >> 6;
    const int lane = threadIdx.x & 63;
    const int row = blockIdx.x * 4 + wave;
    const size_t base = (size_t)row * D + lane * 2;
    const float2 v = *(const float2*)(&W[base]);
    out[1 + base] = v.x;           // out+1 is only 4B-aligned; scalar stores
    out[2 + base] = v.y;
    bf16x2 b;
    b[0] = (__bf16)v.x;
    b[1] = (__bf16)v.y;
    *(bf16x2*)(&Wb[base]) = b;
    float s = v.x * v.x + v.y * v.y;
    for (int off = 32; off > 0; off >>= 1) s += __shfl_down(s, off, 64);
    if (lane == 0) sq[row] = s;
    if (row == 0 && threadIdx.x == 0) out[0] = 0.0f;
}

__global__ __launch_bounds__(256, 4) void lap_kernel(const float* __restrict__ A,
                                                     const __bf16* __restrict__ Wb,
                                                     const float* __restrict__ sq,
                                                     float* __restrict__ out) {
    __shared__ __align__(16) __bf16 dist_lds[BM * DSTRIDE];  // 33.8 KB -> 4 blocks/CU

    const int tid = threadIdx.x;
    const int wave = tid >> 6;
    const int lane = tid & 63;
    const int wr = (wave >> 1) * 64;
    const int wc = (wave & 1) * 64;
    const int l15 = lane & 15;
    const int quad = lane >> 4;
    const int i0 = blockIdx.y * BM;
    const int j0 = blockIdx.x * BN;

    // A/B fragment layout for mfma_f32_16x16x32_bf16: [m = lane&15][k = quad*8 + j]
    const __bf16* Af = Wb + (size_t)(i0 + wr + l15) * D + quad * 8;
    const __bf16* Bf = Wb + (size_t)(j0 + wc + l15) * D + quad * 8;

    f32x4 acc[4][4] = {};
#pragma unroll
    for (int kk = 0; kk < D; kk += 32) {
        bf16x8 a[4], b[4];
#pragma unroll
        for (int ti = 0; ti < 4; ++ti)
            a[ti] = *(const bf16x8*)(Af + (size_t)(ti * 16) * D + kk);
#pragma unroll
        for (int tj = 0; tj < 4; ++tj)
            b[tj] = *(const bf16x8*)(Bf + (size_t)(tj * 16) * D + kk);
#pragma unroll
        for (int ti = 0; ti < 4; ++ti)
#pragma unroll
            for (int tj = 0; tj < 4; ++tj)
                acc[ti][tj] = __builtin_amdgcn_mfma_f32_16x16x32_bf16(a[ti], b[tj], acc[ti][tj], 0, 0, 0);
    }

    // dist = sqrt(max(sq_i + sq_j - 2g, 0)) -> bf16 LDS tile
    // C/D mapping (m89-verified): col = lane&15, row = quad*4 + reg
    float sqi[4][4];
#pragma unroll
    for (int ti = 0; ti < 4; ++ti)
#pragma unroll
        for (int r = 0; r < 4; ++r)
            sqi[ti][r] = sq[i0 + wr + ti * 16 + quad * 4 + r];

#pragma unroll
    for (int ti = 0; ti < 4; ++ti) {
#pragma unroll
        for (int tj = 0; tj < 4; ++tj) {
            const int col = wc + tj * 16 + l15;
            const float sqj = sq[j0 + col];
#pragma unroll
            for (int r = 0; r < 4; ++r) {
                const int row = wr + ti * 16 + quad * 4 + r;
                const float d2 = sqi[ti][r] + sqj - 2.0f * acc[ti][tj][r];
                dist_lds[row * DSTRIDE + col] = (__bf16)sqrtf(fmaxf(d2, 0.0f));
            }
        }
    }
    __syncthreads();

    // A-stream pass: fully-coalesced float4 A loads x bf16x4 dist from LDS
    const int r8 = tid >> 5;          // 0..7
    const int c4 = (tid & 31) * 4;    // 0,4,...,124
    float local = 0.0f;
#pragma unroll
    for (int pass = 0; pass < 16; ++pass) {
        const int row = pass * 8 + r8;
        const float4 av = *(const float4*)(&A[(size_t)(i0 + row) * N + j0 + c4]);
        const bf16x4 dv = *(const bf16x4*)(&dist_lds[row * DSTRIDE + c4]);
        local += av.x * (float)dv[0] + av.y * (float)dv[1]
               + av.z * (float)dv[2] + av.w * (float)dv[3];
    }

    // Block reduce + one atomic per block
    for (int off = 32; off > 0; off >>= 1) local += __shfl_down(local, off, 64);
    __shared__ float red[4];
    if (lane == 0) red[wave] = local;
    __syncthreads();
    if (tid == 0) atomicAdd(out, red[0] + red[1] + red[2] + red[3]);
}

extern "C" void kernel_launch(void* const* d_in, const int* in_sizes, int n_in,
                              void* d_out, int out_size, void* d_ws, size_t ws_size,
                              hipStream_t stream) {
    const float* A = (const float*)d_in[0];
    const float* W = (const float*)d_in[1];
    float* out = (float*)d_out;
    float* sq = (float*)d_ws;                         // 8192 floats = 32 KB
    __bf16* Wb = (__bf16*)((char*)d_ws + 32 * 1024);  // 8192*128 bf16 = 2 MB

    prep_kernel<<<N / 4, 256, 0, stream>>>(W, out, sq, Wb);
    dim3 grid(N / BN, N / BM);
    lap_kernel<<<grid, 256, 0, stream>>>(A, Wb, sq, out);
}